// Round 1
// baseline (243.003 us; speedup 1.0000x reference)
//
#include <hip/hip_runtime.h>
#include <hip/hip_bf16.h>

#define NB 4
#define CC 512
#define TT 4096
#define C3 1536
#define CQK 1024
#define NTC (NB*TT*CC)   // 8388608 elems per [N,T,C] tensor

typedef __attribute__((ext_vector_type(4))) float f32x4;
typedef __attribute__((ext_vector_type(8))) short short8;
typedef unsigned short ushort;
typedef __attribute__((ext_vector_type(8))) ushort u16x8;

__device__ __forceinline__ ushort f2bf(float f){
    union { float f; unsigned u; } x; x.f = f;
    unsigned r = x.u + 0x7fffu + ((x.u >> 16) & 1u);   // RNE
    return (ushort)(r >> 16);
}

__device__ __forceinline__ ushort2 pk2bf(float a, float b){
    float2 f2; f2.x = a; f2.y = b;
    __hip_bfloat162 h = __float22bfloat162_rn(f2);     // v_cvt_pk_bf16_f32 (RNE)
    union { __hip_bfloat162 h2; ushort2 u2; } u; u.h2 = h;
    return u.u2;
}

__device__ __forceinline__ void gload16(const void* g, void* l){
    __builtin_amdgcn_global_load_lds((const __attribute__((address_space(1))) void*)g,
                                     (__attribute__((address_space(3))) void*)l,
                                     16, 0, 0);
}

// sA swizzle: 16B slot position for logical c-block cb at row m.
__device__ __forceinline__ int apos(int m, int cb){
    return (m*8 + ((cb + m + (m >> 3)) & 7))*8;
}

// ---------------- K0: weight fp32 -> bf16 ----------------
__global__ __launch_bounds__(256) void wcvt(const float* __restrict__ Wi,
                                            const float* __restrict__ Wo,
                                            ushort* __restrict__ Wb,
                                            ushort* __restrict__ Wob){
    int idx0 = blockIdx.x * 1024 + threadIdx.x;
    for (int i = 0; i < 4; ++i){
        int idx = idx0 + i*256;
        const float* src; ushort* dst; int j;
        if (idx < 196608){ src = Wi; dst = Wb;  j = idx; }
        else             { src = Wo; dst = Wob; j = idx - 196608; }
        f32x4 vv = *((const f32x4*)src + j);
        ushort4 o;
        *(ushort2*)&o.x = pk2bf(vv[0], vv[1]);
        *(ushort2*)&o.z = pk2bf(vv[2], vv[3]);
        *((ushort4*)dst + j) = o;
    }
}

// ---------------- K1: fused transpose+cvt + QKV projection GEMM ----------------
// A is REG-staged (global fp32 -> regs as c-pairs -> pk2bf -> ds_write to
// swizzled sA). No fp32 LDS staging buffer: LDS 80KB -> 48KB => 3 blocks/CU.
// Prefetch for kb+1 (A regs + B async) issued before MFMA(kb) so the B1 drain
// waits exactly what the next phase needs.
__global__ __launch_bounds__(256, 3) void proj_gemm(const float* __restrict__ q,
                                                    const float* __restrict__ k,
                                                    const float* __restrict__ v,
                                                    const ushort* __restrict__ Wb,
                                                    const float* __restrict__ b_in,
                                                    ushort* __restrict__ P,
                                                    ushort* __restrict__ Vt){
    __shared__ __align__(16) ushort smem[24576];   // 48 KB
    ushort* sA  = smem;            // 16 KB  (bf16 A, swizzled, single buffer)
    ushort* sB0 = smem + 8192;     // 16 KB
    ushort* sB1 = smem + 16384;    // 16 KB
    const int tid = threadIdx.x;
    const int bid = blockIdx.x;
    const int mtile  = ((bid & 7) << 4) | ((bid >> 3) & 15);
    const int cotile = bid >> 7;               // 0..11
    const int co0 = cotile * 128;
    const int m0  = mtile * 128;
    const int which = co0 >> 9;                // 0:q 1:k 2:v
    const float* src = (which == 0) ? q : (which == 1) ? k : v;
    const int n  = m0 >> 12, t0 = m0 & 4095;
    const ushort* Bbase = Wb + (size_t)co0*CC;
    const int w = tid >> 6, lane = tid & 63;
    const int wr = w >> 1, wc = w & 1;
    const int l15 = lane & 15, quad = lane >> 4;
    const int hlf = lane >> 5, tq = lane & 31;

    // ---- B async staging: kk is independent of the i-group (i*32 % 8 == 0) ----
    const int mrB = tid >> 3;
    const int kkB = (tid & 7) ^ (mrB & 7);
    const ushort* gB0 = Bbase + (size_t)mrB*CC + kkB*8;
    const int lB0 = (tid & ~63) * 8;

    // ---- A reg-staging: thread owns 4 units = c-pair (ce, ce+1) x t-quad ----
    const float* Ab = src + (size_t)n*CC*TT + t0 + tq*4;
    const int ce0 = w*16 + hlf*2;              // + u*4 per unit

    f32x4 a0[4], a1[4];
    // prologue: kb=0
    #pragma unroll
    for (int u = 0; u < 4; ++u){
        a0[u] = *(const f32x4*)(Ab + (size_t)(ce0 + u*4    )*TT);
        a1[u] = *(const f32x4*)(Ab + (size_t)(ce0 + u*4 + 1)*TT);
    }
    #pragma unroll
    for (int i = 0; i < 4; ++i)
        gload16(gB0 + (size_t)i*32*CC, sB0 + lB0 + i*2048);
    #pragma unroll
    for (int u = 0; u < 4; ++u){
        int ce = ce0 + u*4;
        int cb = ce >> 3, off = ce & 7;
        #pragma unroll
        for (int j = 0; j < 4; ++j)
            *(ushort2*)&sA[apos(tq*4 + j, cb) + off] = pk2bf(a0[u][j], a1[u][j]);
    }
    __syncthreads();

    f32x4 acc[4][4] = {};
    for (int kb = 0; kb < 8; ++kb){
        ushort* sBc = (kb & 1) ? sB1 : sB0;
        ushort* sBn = (kb & 1) ? sB0 : sB1;
        if (kb < 7){               // prefetch kb+1 BEFORE MFMA: latency cover
            const float* Abn = Ab + (size_t)((kb+1)*64)*TT;
            #pragma unroll
            for (int u = 0; u < 4; ++u){
                a0[u] = *(const f32x4*)(Abn + (size_t)(ce0 + u*4    )*TT);
                a1[u] = *(const f32x4*)(Abn + (size_t)(ce0 + u*4 + 1)*TT);
            }
            #pragma unroll
            for (int i = 0; i < 4; ++i)
                gload16(gB0 + (size_t)i*32*CC + (kb+1)*64, sBn + lB0 + i*2048);
        }
        #pragma unroll
        for (int ks = 0; ks < 2; ++ks){
            short8 aF[4], bF[4];
            #pragma unroll
            for (int mi = 0; mi < 4; ++mi){
                int m = wr*64 + mi*16 + l15;
                aF[mi] = *(const short8*)&sA[apos(m, ks*4 + quad)];
            }
            #pragma unroll
            for (int ni = 0; ni < 4; ++ni){
                int m = wc*64 + ni*16 + l15;
                bF[ni] = *(const short8*)&sBc[(m*8 + ((ks*4 + quad) ^ (m & 7)))*8];
            }
            #pragma unroll
            for (int mi = 0; mi < 4; ++mi)
                #pragma unroll
                for (int ni = 0; ni < 4; ++ni)
                    acc[mi][ni] = __builtin_amdgcn_mfma_f32_16x16x32_bf16(
                        aF[mi], bF[ni], acc[mi][ni], 0, 0, 0);
        }
        __syncthreads();           // B1: sA readers done; kb+1 loads drained here
        if (kb < 7){               // cvt + transposed write of A(kb+1)
            #pragma unroll
            for (int u = 0; u < 4; ++u){
                int ce = ce0 + u*4;
                int cb = ce >> 3, off = ce & 7;
                #pragma unroll
                for (int j = 0; j < 4; ++j)
                    *(ushort2*)&sA[apos(tq*4 + j, cb) + off] = pk2bf(a0[u][j], a1[u][j]);
            }
        }
        __syncthreads();           // B2: sA(kb+1) visible
    }

    float bj[4];
    for (int ni = 0; ni < 4; ++ni) bj[ni] = b_in[co0 + wc*64 + ni*16 + l15];

    __syncthreads();                 // done with staging; reuse as sOut[128][136]
    ushort* sOut = smem;
    if (which < 2){
        for (int mi = 0; mi < 4; ++mi){
            int mrow = wr*64 + mi*16 + quad*4;
            for (int ni = 0; ni < 4; ++ni){
                int col = wc*64 + ni*16 + l15;
                for (int r = 0; r < 4; ++r)
                    sOut[(mrow + r)*136 + col] = f2bf(acc[mi][ni][r] + bj[ni]);
            }
        }
    } else {
        for (int mi = 0; mi < 4; ++mi){
            int mrow = wr*64 + mi*16 + quad*4;
            for (int ni = 0; ni < 4; ++ni){
                int col = wc*64 + ni*16 + l15;
                ushort4 o4;
                o4.x = f2bf(acc[mi][ni][0] + bj[ni]);
                o4.y = f2bf(acc[mi][ni][1] + bj[ni]);
                o4.z = f2bf(acc[mi][ni][2] + bj[ni]);
                o4.w = f2bf(acc[mi][ni][3] + bj[ni]);
                *(ushort4*)&sOut[col*136 + mrow] = o4;   // mrow%4==0, contiguous
            }
        }
    }
    __syncthreads();
    if (which < 2){
        for (int i = 0; i < 8; ++i){
            int flat = i*256 + tid;
            int row = flat >> 4, cs = (flat & 15)*8;
            u16x8 val = *(const u16x8*)&sOut[row*136 + cs];
            *(u16x8*)(P + (size_t)(m0 + row)*CQK + which*512 + (co0 & 511) + cs) = val;
        }
    } else {
        for (int i = 0; i < 8; ++i){
            int flat = i*256 + tid;
            int row = flat >> 4, cs = (flat & 15)*8;    // row = local co (d), cs along t
            int cl = (co0 - 1024) + row;
            int h = cl >> 6, d = cl & 63;
            u16x8 val = *(const u16x8*)&sOut[row*136 + cs];
            *(u16x8*)(Vt + (((size_t)n*8 + h)*64 + d)*TT + t0 + cs) = val;
        }
    }
}

// ---------------- K2: per-(n,chunk,head) attention (LDS epilogue) ----------------
__global__ __launch_bounds__(256) void attn_kernel(const ushort* __restrict__ P,
                                                   const ushort* __restrict__ Vt,
                                                   const float* __restrict__ masks,
                                                   ushort* __restrict__ ctx){
    __shared__ __align__(16) ushort sQ[64*64], sK[64*64], sV[64*64];   // swizzled
    __shared__ __align__(16) ushort sP[64][72];
    __shared__ __align__(16) ushort sO[64*72];
    int bid = blockIdx.x;
    int h = bid & 7, ch = (bid >> 3) & 63, n = bid >> 9;
    const int tid = threadIdx.x, lane = tid & 63, w = tid >> 6;
    const int l15 = lane & 15, quad = lane >> 4;
    const size_t rowbase = (size_t)n*TT + (size_t)ch*64;
    for (int i = 0; i < 2; ++i){
        int slot = i*256 + tid;
        int r = slot >> 3, k8 = slot & 7, kk = k8 ^ (r & 7);
        int lbase = (i*256 + (tid & ~63)) * 8;
        const ushort* gq = P + (rowbase + r)*CQK + h*64 + kk*8;
        gload16(gq,        sQ + lbase);
        gload16(gq + 512,  sK + lbase);
        const ushort* gv = Vt + (((size_t)n*8 + h)*64 + r)*TT + ch*64 + kk*8;
        gload16(gv,        sV + lbase);
    }
    __syncthreads();
    const int m0w = w*16;
    short8 aQ[2]; f32x4 accS[4] = {};
    for (int ks = 0; ks < 2; ++ks){
        int m = m0w + l15;
        aQ[ks] = *(const short8*)&sQ[(m*8 + ((ks*4 + quad) ^ (m & 7)))*8];
    }
    for (int ni = 0; ni < 4; ++ni)
        for (int ks = 0; ks < 2; ++ks){
            int m = ni*16 + l15;
            short8 bK = *(const short8*)&sK[(m*8 + ((ks*4 + quad) ^ (m & 7)))*8];
            accS[ni] = __builtin_amdgcn_mfma_f32_16x16x32_bf16(aQ[ks], bK, accS[ni], 0,0,0);
        }
    float madd[4];
    for (int ni = 0; ni < 4; ++ni){
        float mv = masks[(size_t)n*TT + ch*64 + ni*16 + l15];
        madd[ni] = (mv > 0.f) ? 0.f : -1e9f;
    }
    float s[4][4];
    for (int ni = 0; ni < 4; ++ni)
        for (int r = 0; r < 4; ++r) s[ni][r] = accS[ni][r]*0.125f + madd[ni];
    float ex[4][4];
    for (int r = 0; r < 4; ++r){
        float m1 = fmaxf(fmaxf(s[0][r], s[1][r]), fmaxf(s[2][r], s[3][r]));
        for (int d = 1; d < 16; d <<= 1) m1 = fmaxf(m1, __shfl_xor(m1, d));
        float a = 0.f;
        for (int ni = 0; ni < 4; ++ni){ float e = __expf(s[ni][r] - m1); ex[ni][r] = e; a += e; }
        for (int d = 1; d < 16; d <<= 1) a += __shfl_xor(a, d);
        float rs = 1.0f / a;
        for (int ni = 0; ni < 4; ++ni)
            sP[m0w + quad*4 + r][ni*16 + l15] = f2bf(ex[ni][r] * rs);
    }
    short8 aP[2]; f32x4 accO[4] = {};
    for (int ks = 0; ks < 2; ++ks)
        aP[ks] = *(const short8*)&sP[m0w + l15][ks*32 + quad*8];
    for (int ni = 0; ni < 4; ++ni)
        for (int ks = 0; ks < 2; ++ks){
            int m = ni*16 + l15;
            short8 bV = *(const short8*)&sV[(m*8 + ((ks*4 + quad) ^ (m & 7)))*8];
            accO[ni] = __builtin_amdgcn_mfma_f32_16x16x32_bf16(aP[ks], bV, accO[ni], 0,0,0);
        }
    for (int ni = 0; ni < 4; ++ni)
        for (int r = 0; r < 4; ++r)
            sO[(m0w + quad*4 + r)*72 + ni*16 + l15] = f2bf(accO[ni][r]);
    __syncthreads();
    for (int i = 0; i < 2; ++i){
        int flat = i*256 + tid;
        int row = flat >> 3, cs = (flat & 7)*8;
        u16x8 val = *(const u16x8*)&sO[row*72 + cs];
        *(u16x8*)(ctx + (rowbase + row)*CC + h*64 + cs) = val;
    }
}

// ---------------- K3: out-projection, 128m x 64co tiles, double-buffered ----------------
// A+B async double-buffered, prefetch(kb+1) issued BEFORE MFMA(kb); one barrier
// per K-step (the barrier at the top of kb+1 is the landing wait for its bufs).
__global__ __launch_bounds__(256) void out_gemm(const ushort* __restrict__ ctx,
                                                const ushort* __restrict__ Wob,
                                                const float* __restrict__ b_out,
                                                const float* __restrict__ x,
                                                const float* __restrict__ masks,
                                                float* __restrict__ out){
    __shared__ __align__(16) ushort smem[24576];   // 48 KB: A dbuf 32K + B dbuf 16K
    ushort* sA0 = smem;            // 16 KB
    ushort* sA1 = smem + 8192;     // 16 KB
    ushort* sB0 = smem + 16384;    //  8 KB
    ushort* sB1 = smem + 20480;    //  8 KB
    float* fOut = (float*)smem;    // epilogue reuse: [64 co][132] f32 (33.8 KB)
    const int tid = threadIdx.x;
    const int bid = blockIdx.x;
    const int mtile  = ((bid & 7) << 4) | ((bid >> 3) & 15);
    const int cotile = bid >> 7;               // 0..7
    const int co0 = cotile * 64;
    const int m0  = mtile * 128;
    const int n = m0 >> 12, t0 = m0 & 4095;
    const ushort* Abase = ctx + (size_t)m0*CC;
    const ushort* Bbase = Wob + (size_t)co0*CC;
    const int w = tid >> 6, lane = tid & 63;
    const int wr = w >> 1, wc = w & 1;
    const int l15 = lane & 15, quad = lane >> 4;

    const int mr = tid >> 3;
    const int kk = (tid & 7) ^ (mr & 7);
    const ushort* gA0 = Abase + (size_t)mr*CC + kk*8;
    const ushort* gB0 = Bbase + (size_t)mr*CC + kk*8;
    const int lS = (tid & ~63) * 8;

    // prologue: kb=0 into buf0
    #pragma unroll
    for (int i = 0; i < 4; ++i) gload16(gA0 + (size_t)i*32*CC, sA0 + lS + i*2048);
    #pragma unroll
    for (int i = 0; i < 2; ++i) gload16(gB0 + (size_t)i*32*CC, sB0 + lS + i*2048);

    f32x4 acc[4][2] = {};
    for (int kb = 0; kb < 8; ++kb){
        ushort* sAc = (kb & 1) ? sA1 : sA0;
        ushort* sBc = (kb & 1) ? sB1 : sB0;
        ushort* sAn = (kb & 1) ? sA0 : sA1;
        ushort* sBn = (kb & 1) ? sB0 : sB1;
        __syncthreads();           // buf(kb) landed+visible; MFMA(kb-1) readers done
        if (kb < 7){
            #pragma unroll
            for (int i = 0; i < 4; ++i)
                gload16(gA0 + (size_t)i*32*CC + (kb+1)*64, sAn + lS + i*2048);
            #pragma unroll
            for (int i = 0; i < 2; ++i)
                gload16(gB0 + (size_t)i*32*CC + (kb+1)*64, sBn + lS + i*2048);
        }
        #pragma unroll
        for (int ks = 0; ks < 2; ++ks){
            short8 aF[4], bF[2];
            #pragma unroll
            for (int mi = 0; mi < 4; ++mi){
                int m = wr*64 + mi*16 + l15;
                aF[mi] = *(const short8*)&sAc[(m*8 + ((ks*4 + quad) ^ (m & 7)))*8];
            }
            #pragma unroll
            for (int ni = 0; ni < 2; ++ni){
                int m = wc*32 + ni*16 + l15;
                bF[ni] = *(const short8*)&sBc[(m*8 + ((ks*4 + quad) ^ (m & 7)))*8];
            }
            #pragma unroll
            for (int mi = 0; mi < 4; ++mi)
                #pragma unroll
                for (int ni = 0; ni < 2; ++ni)
                    acc[mi][ni] = __builtin_amdgcn_mfma_f32_16x16x32_bf16(
                        aF[mi], bF[ni], acc[mi][ni], 0, 0, 0);
        }
    }
    float bo[2];
    for (int ni = 0; ni < 2; ++ni) bo[ni] = b_out[co0 + wc*32 + ni*16 + l15];

    __syncthreads();                 // staging done; reuse LDS as fOut[co][t]
    for (int mi = 0; mi < 4; ++mi){
        int tl = wr*64 + mi*16 + quad*4;
        for (int ni = 0; ni < 2; ++ni){
            int cl = wc*32 + ni*16 + l15;
            f32x4 vv;
            for (int r = 0; r < 4; ++r) vv[r] = acc[mi][ni][r] + bo[ni];
            *(f32x4*)&fOut[cl*132 + tl] = vv;
        }
    }
    __syncthreads();
    for (int i = 0; i < 8; ++i){
        int flat = i*256 + tid;
        int co = flat >> 5, ts = (flat & 31)*4;
        f32x4 a = *(const f32x4*)&fOut[co*132 + ts];
        f32x4 mk = *(const f32x4*)(masks + (size_t)n*TT + t0 + ts);
        f32x4 xv = *(const f32x4*)(x + ((size_t)n*CC + co0 + co)*TT + t0 + ts);
        f32x4 o;
        for (int r = 0; r < 4; ++r) o[r] = a[r]*mk[r] + xv[r];
        *(f32x4*)(out + ((size_t)n*CC + co0 + co)*TT + t0 + ts) = o;
    }
}

// ---------------- K4: InstanceNorm over T per (n,c), in place ----------------
__global__ __launch_bounds__(256) void inorm(float* __restrict__ out){
    __shared__ float sS[4], sQ2[4];
    float* row = out + (size_t)blockIdx.x * TT;
    f32x4 vbuf[4];
    float s = 0.f, ss = 0.f;
    for (int i = 0; i < 4; ++i){
        f32x4 vv = *(const f32x4*)(row + (size_t)(i*256 + threadIdx.x)*4);
        vbuf[i] = vv;
        for (int r = 0; r < 4; ++r){ s += vv[r]; ss += vv[r]*vv[r]; }
    }
    for (int d = 1; d < 64; d <<= 1){ s += __shfl_xor(s, d); ss += __shfl_xor(ss, d); }
    int w = threadIdx.x >> 6;
    if ((threadIdx.x & 63) == 0){ sS[w] = s; sQ2[w] = ss; }
    __syncthreads();
    s  = sS[0] + sS[1] + sS[2] + sS[3];
    ss = sQ2[0] + sQ2[1] + sQ2[2] + sQ2[3];
    float mean = s * (1.0f/TT);
    float var  = ss * (1.0f/TT) - mean*mean;
    float rstd = rsqrtf(var + 1e-5f);
    for (int i = 0; i < 4; ++i){
        f32x4 vv = vbuf[i], o;
        for (int r = 0; r < 4; ++r) o[r] = (vv[r] - mean) * rstd;
        *(f32x4*)(row + (size_t)(i*256 + threadIdx.x)*4) = o;
    }
}

extern "C" void kernel_launch(void* const* d_in, const int* in_sizes, int n_in,
                              void* d_out, int out_size, void* d_ws, size_t ws_size,
                              hipStream_t stream) {
    const float* x     = (const float*)d_in[0];
    const float* q     = (const float*)d_in[1];
    const float* k     = (const float*)d_in[2];
    const float* v     = (const float*)d_in[3];
    const float* masks = (const float*)d_in[4];
    const float* W_in  = (const float*)d_in[5];
    const float* b_in  = (const float*)d_in[6];
    const float* W_out = (const float*)d_in[7];
    const float* b_out = (const float*)d_in[8];
    float* out = (float*)d_out;

    ushort* ws  = (ushort*)d_ws;
    ushort* ctx = ws;                           // NTC bf16 (attention output)
    ushort* Wb  = ws + (size_t)NTC;             // 786432
    ushort* Wob = Wb + 786432;                  // 262144
    ushort* P   = Wob + 262144;                 // NB*TT*CQK (Q,K projected)
    ushort* Vt  = P + (size_t)NB*TT*CQK;        // NTC (V projected, transposed)

    wcvt<<<256, 256, 0, stream>>>(W_in, W_out, Wb, Wob);
    proj_gemm<<<1536, 256, 0, stream>>>(q, k, v, Wb, b_in, P, Vt);
    attn_kernel<<<2048, 256, 0, stream>>>(P, Vt, masks, ctx);
    out_gemm<<<1024, 256, 0, stream>>>(ctx, Wob, b_out, x, masks, out);
    inorm<<<2048, 256, 0, stream>>>(out);
}

// Round 2
// 242.184 us; speedup vs baseline: 1.0034x; 1.0034x over previous
//
#include <hip/hip_runtime.h>
#include <hip/hip_bf16.h>

#define NB 4
#define CC 512
#define TT 4096
#define C3 1536
#define CQK 1024
#define NTC (NB*TT*CC)   // 8388608 elems per [N,T,C] tensor

typedef __attribute__((ext_vector_type(4))) float f32x4;
typedef __attribute__((ext_vector_type(8))) short short8;
typedef unsigned short ushort;
typedef __attribute__((ext_vector_type(8))) ushort u16x8;

__device__ __forceinline__ ushort f2bf(float f){
    union { float f; unsigned u; } x; x.f = f;
    unsigned r = x.u + 0x7fffu + ((x.u >> 16) & 1u);   // RNE
    return (ushort)(r >> 16);
}

__device__ __forceinline__ ushort2 pk2bf(float a, float b){
    float2 f2; f2.x = a; f2.y = b;
    __hip_bfloat162 h = __float22bfloat162_rn(f2);     // v_cvt_pk_bf16_f32 (RNE)
    union { __hip_bfloat162 h2; ushort2 u2; } u; u.h2 = h;
    return u.u2;
}

__device__ __forceinline__ void gload16(const void* g, void* l){
    __builtin_amdgcn_global_load_lds((const __attribute__((address_space(1))) void*)g,
                                     (__attribute__((address_space(3))) void*)l,
                                     16, 0, 0);
}

// sA swizzle: 16B slot position for logical c-block cb at row m.
__device__ __forceinline__ int apos(int m, int cb){
    return (m*8 + ((cb + m + (m >> 3)) & 7))*8;
}

// ---------------- K0: weight fp32 -> bf16 ----------------
__global__ __launch_bounds__(256) void wcvt(const float* __restrict__ Wi,
                                            const float* __restrict__ Wo,
                                            ushort* __restrict__ Wb,
                                            ushort* __restrict__ Wob){
    int idx0 = blockIdx.x * 1024 + threadIdx.x;
    for (int i = 0; i < 4; ++i){
        int idx = idx0 + i*256;
        const float* src; ushort* dst; int j;
        if (idx < 196608){ src = Wi; dst = Wb;  j = idx; }
        else             { src = Wo; dst = Wob; j = idx - 196608; }
        f32x4 vv = *((const f32x4*)src + j);
        ushort4 o;
        *(ushort2*)&o.x = pk2bf(vv[0], vv[1]);
        *(ushort2*)&o.z = pk2bf(vv[2], vv[3]);
        *((ushort4*)dst + j) = o;
    }
}

// ---------------- K1: fused transpose+cvt + QKV projection GEMM ----------------
// A reg-staged (fp32 -> regs -> pk2bf -> swizzled sA). 48 KB LDS, 3 blocks/CU.
// Block-index swizzle: cotile-FASTEST within an XCD chunk, so the 12 cotile
// blocks sharing one A m-slab are co-resident on one XCD -> A loads hit the
// per-XCD L2 (~200cy) instead of L3/HBM (~600-900cy); the existing MFMA-phase
// prefetch window then fully covers the latency.
__global__ __launch_bounds__(256, 3) void proj_gemm(const float* __restrict__ q,
                                                    const float* __restrict__ k,
                                                    const float* __restrict__ v,
                                                    const ushort* __restrict__ Wb,
                                                    const float* __restrict__ b_in,
                                                    ushort* __restrict__ P,
                                                    ushort* __restrict__ Vt){
    __shared__ __align__(16) ushort smem[24576];   // 48 KB
    ushort* sA  = smem;            // 16 KB  (bf16 A, swizzled, single buffer)
    ushort* sB0 = smem + 8192;     // 16 KB
    ushort* sB1 = smem + 16384;    // 16 KB
    const int tid = threadIdx.x;
    const int bid = blockIdx.x;
    // temporal XCD swizzle: 1536 blocks, 8 XCDs, 192 per chunk; cot fastest.
    const int l = (bid & 7)*192 + (bid >> 3);
    const int cotile = l % 12;                 // 0..11
    const int mtile  = l / 12;                 // 0..127
    const int co0 = cotile * 128;
    const int m0  = mtile * 128;
    const int which = co0 >> 9;                // 0:q 1:k 2:v
    const float* src = (which == 0) ? q : (which == 1) ? k : v;
    const int n  = m0 >> 12, t0 = m0 & 4095;
    const ushort* Bbase = Wb + (size_t)co0*CC;
    const int w = tid >> 6, lane = tid & 63;
    const int wr = w >> 1, wc = w & 1;
    const int l15 = lane & 15, quad = lane >> 4;
    const int hlf = lane >> 5, tq = lane & 31;

    // ---- B async staging: kk is independent of the i-group (i*32 % 8 == 0) ----
    const int mrB = tid >> 3;
    const int kkB = (tid & 7) ^ (mrB & 7);
    const ushort* gB0 = Bbase + (size_t)mrB*CC + kkB*8;
    const int lB0 = (tid & ~63) * 8;

    // ---- A reg-staging: thread owns 4 units = c-pair (ce, ce+1) x t-quad ----
    const float* Ab = src + (size_t)n*CC*TT + t0 + tq*4;
    const int ce0 = w*16 + hlf*2;              // + u*4 per unit

    f32x4 a0[4], a1[4];
    // prologue: kb=0
    #pragma unroll
    for (int u = 0; u < 4; ++u){
        a0[u] = *(const f32x4*)(Ab + (size_t)(ce0 + u*4    )*TT);
        a1[u] = *(const f32x4*)(Ab + (size_t)(ce0 + u*4 + 1)*TT);
    }
    #pragma unroll
    for (int i = 0; i < 4; ++i)
        gload16(gB0 + (size_t)i*32*CC, sB0 + lB0 + i*2048);
    #pragma unroll
    for (int u = 0; u < 4; ++u){
        int ce = ce0 + u*4;
        int cb = ce >> 3, off = ce & 7;
        #pragma unroll
        for (int j = 0; j < 4; ++j)
            *(ushort2*)&sA[apos(tq*4 + j, cb) + off] = pk2bf(a0[u][j], a1[u][j]);
    }
    __syncthreads();

    f32x4 acc[4][4] = {};
    for (int kb = 0; kb < 8; ++kb){
        ushort* sBc = (kb & 1) ? sB1 : sB0;
        ushort* sBn = (kb & 1) ? sB0 : sB1;
        if (kb < 7){               // prefetch kb+1 BEFORE MFMA: latency cover
            const float* Abn = Ab + (size_t)((kb+1)*64)*TT;
            #pragma unroll
            for (int u = 0; u < 4; ++u){
                a0[u] = *(const f32x4*)(Abn + (size_t)(ce0 + u*4    )*TT);
                a1[u] = *(const f32x4*)(Abn + (size_t)(ce0 + u*4 + 1)*TT);
            }
            #pragma unroll
            for (int i = 0; i < 4; ++i)
                gload16(gB0 + (size_t)i*32*CC + (kb+1)*64, sBn + lB0 + i*2048);
        }
        #pragma unroll
        for (int ks = 0; ks < 2; ++ks){
            short8 aF[4], bF[4];
            #pragma unroll
            for (int mi = 0; mi < 4; ++mi){
                int m = wr*64 + mi*16 + l15;
                aF[mi] = *(const short8*)&sA[apos(m, ks*4 + quad)];
            }
            #pragma unroll
            for (int ni = 0; ni < 4; ++ni){
                int m = wc*64 + ni*16 + l15;
                bF[ni] = *(const short8*)&sBc[(m*8 + ((ks*4 + quad) ^ (m & 7)))*8];
            }
            #pragma unroll
            for (int mi = 0; mi < 4; ++mi)
                #pragma unroll
                for (int ni = 0; ni < 4; ++ni)
                    acc[mi][ni] = __builtin_amdgcn_mfma_f32_16x16x32_bf16(
                        aF[mi], bF[ni], acc[mi][ni], 0, 0, 0);
        }
        __syncthreads();           // B1: sA readers done; kb+1 loads drained here
        if (kb < 7){               // cvt + transposed write of A(kb+1)
            #pragma unroll
            for (int u = 0; u < 4; ++u){
                int ce = ce0 + u*4;
                int cb = ce >> 3, off = ce & 7;
                #pragma unroll
                for (int j = 0; j < 4; ++j)
                    *(ushort2*)&sA[apos(tq*4 + j, cb) + off] = pk2bf(a0[u][j], a1[u][j]);
            }
        }
        __syncthreads();           // B2: sA(kb+1) visible
    }

    float bj[4];
    for (int ni = 0; ni < 4; ++ni) bj[ni] = b_in[co0 + wc*64 + ni*16 + l15];

    __syncthreads();                 // done with staging; reuse as sOut[128][136]
    ushort* sOut = smem;
    if (which < 2){
        for (int mi = 0; mi < 4; ++mi){
            int mrow = wr*64 + mi*16 + quad*4;
            for (int ni = 0; ni < 4; ++ni){
                int col = wc*64 + ni*16 + l15;
                for (int r = 0; r < 4; ++r)
                    sOut[(mrow + r)*136 + col] = f2bf(acc[mi][ni][r] + bj[ni]);
            }
        }
    } else {
        for (int mi = 0; mi < 4; ++mi){
            int mrow = wr*64 + mi*16 + quad*4;
            for (int ni = 0; ni < 4; ++ni){
                int col = wc*64 + ni*16 + l15;
                ushort4 o4;
                o4.x = f2bf(acc[mi][ni][0] + bj[ni]);
                o4.y = f2bf(acc[mi][ni][1] + bj[ni]);
                o4.z = f2bf(acc[mi][ni][2] + bj[ni]);
                o4.w = f2bf(acc[mi][ni][3] + bj[ni]);
                *(ushort4*)&sOut[col*136 + mrow] = o4;   // mrow%4==0, contiguous
            }
        }
    }
    __syncthreads();
    if (which < 2){
        for (int i = 0; i < 8; ++i){
            int flat = i*256 + tid;
            int row = flat >> 4, cs = (flat & 15)*8;
            u16x8 val = *(const u16x8*)&sOut[row*136 + cs];
            *(u16x8*)(P + (size_t)(m0 + row)*CQK + which*512 + (co0 & 511) + cs) = val;
        }
    } else {
        for (int i = 0; i < 8; ++i){
            int flat = i*256 + tid;
            int row = flat >> 4, cs = (flat & 15)*8;    // row = local co (d), cs along t
            int cl = (co0 - 1024) + row;
            int h = cl >> 6, d = cl & 63;
            u16x8 val = *(const u16x8*)&sOut[row*136 + cs];
            *(u16x8*)(Vt + (((size_t)n*8 + h)*64 + d)*TT + t0 + cs) = val;
        }
    }
}

// ---------------- K2: per-(n,chunk,head) attention (LDS epilogue) ----------------
// Swizzle: the 8 head-blocks sharing one (n,ch) P-slab (128 KB) run adjacent
// on the same XCD for L2 reuse.
__global__ __launch_bounds__(256) void attn_kernel(const ushort* __restrict__ P,
                                                   const ushort* __restrict__ Vt,
                                                   const float* __restrict__ masks,
                                                   ushort* __restrict__ ctx){
    __shared__ __align__(16) ushort sQ[64*64], sK[64*64], sV[64*64];   // swizzled
    __shared__ __align__(16) ushort sP[64][72];
    __shared__ __align__(16) ushort sO[64*72];
    int bid = blockIdx.x;
    int l = (bid & 7)*256 + (bid >> 3);        // 2048 blocks, h fastest per XCD
    int h = l & 7, ch = (l >> 3) & 63, n = l >> 9;
    const int tid = threadIdx.x, lane = tid & 63, w = tid >> 6;
    const int l15 = lane & 15, quad = lane >> 4;
    const size_t rowbase = (size_t)n*TT + (size_t)ch*64;
    for (int i = 0; i < 2; ++i){
        int slot = i*256 + tid;
        int r = slot >> 3, k8 = slot & 7, kk = k8 ^ (r & 7);
        int lbase = (i*256 + (tid & ~63)) * 8;
        const ushort* gq = P + (rowbase + r)*CQK + h*64 + kk*8;
        gload16(gq,        sQ + lbase);
        gload16(gq + 512,  sK + lbase);
        const ushort* gv = Vt + (((size_t)n*8 + h)*64 + r)*TT + ch*64 + kk*8;
        gload16(gv,        sV + lbase);
    }
    __syncthreads();
    const int m0w = w*16;
    short8 aQ[2]; f32x4 accS[4] = {};
    for (int ks = 0; ks < 2; ++ks){
        int m = m0w + l15;
        aQ[ks] = *(const short8*)&sQ[(m*8 + ((ks*4 + quad) ^ (m & 7)))*8];
    }
    for (int ni = 0; ni < 4; ++ni)
        for (int ks = 0; ks < 2; ++ks){
            int m = ni*16 + l15;
            short8 bK = *(const short8*)&sK[(m*8 + ((ks*4 + quad) ^ (m & 7)))*8];
            accS[ni] = __builtin_amdgcn_mfma_f32_16x16x32_bf16(aQ[ks], bK, accS[ni], 0,0,0);
        }
    float madd[4];
    for (int ni = 0; ni < 4; ++ni){
        float mv = masks[(size_t)n*TT + ch*64 + ni*16 + l15];
        madd[ni] = (mv > 0.f) ? 0.f : -1e9f;
    }
    float s[4][4];
    for (int ni = 0; ni < 4; ++ni)
        for (int r = 0; r < 4; ++r) s[ni][r] = accS[ni][r]*0.125f + madd[ni];
    float ex[4][4];
    for (int r = 0; r < 4; ++r){
        float m1 = fmaxf(fmaxf(s[0][r], s[1][r]), fmaxf(s[2][r], s[3][r]));
        for (int d = 1; d < 16; d <<= 1) m1 = fmaxf(m1, __shfl_xor(m1, d));
        float a = 0.f;
        for (int ni = 0; ni < 4; ++ni){ float e = __expf(s[ni][r] - m1); ex[ni][r] = e; a += e; }
        for (int d = 1; d < 16; d <<= 1) a += __shfl_xor(a, d);
        float rs = 1.0f / a;
        for (int ni = 0; ni < 4; ++ni)
            sP[m0w + quad*4 + r][ni*16 + l15] = f2bf(ex[ni][r] * rs);
    }
    short8 aP[2]; f32x4 accO[4] = {};
    for (int ks = 0; ks < 2; ++ks)
        aP[ks] = *(const short8*)&sP[m0w + l15][ks*32 + quad*8];
    for (int ni = 0; ni < 4; ++ni)
        for (int ks = 0; ks < 2; ++ks){
            int m = ni*16 + l15;
            short8 bV = *(const short8*)&sV[(m*8 + ((ks*4 + quad) ^ (m & 7)))*8];
            accO[ni] = __builtin_amdgcn_mfma_f32_16x16x32_bf16(aP[ks], bV, accO[ni], 0,0,0);
        }
    for (int ni = 0; ni < 4; ++ni)
        for (int r = 0; r < 4; ++r)
            sO[(m0w + quad*4 + r)*72 + ni*16 + l15] = f2bf(accO[ni][r]);
    __syncthreads();
    for (int i = 0; i < 2; ++i){
        int flat = i*256 + tid;
        int row = flat >> 3, cs = (flat & 7)*8;
        u16x8 val = *(const u16x8*)&sO[row*72 + cs];
        *(u16x8*)(ctx + (rowbase + row)*CC + h*64 + cs) = val;
    }
}

// ---------------- K3: out-projection, 128m x 64co tiles, double-buffered ----------------
// Swizzle: the 8 cotile-blocks sharing one ctx m-slab (128 KB) run adjacent on
// the same XCD for L2 reuse.
__global__ __launch_bounds__(256) void out_gemm(const ushort* __restrict__ ctx,
                                                const ushort* __restrict__ Wob,
                                                const float* __restrict__ b_out,
                                                const float* __restrict__ x,
                                                const float* __restrict__ masks,
                                                float* __restrict__ out){
    __shared__ __align__(16) ushort smem[24576];   // 48 KB: A dbuf 32K + B dbuf 16K
    ushort* sA0 = smem;            // 16 KB
    ushort* sA1 = smem + 8192;     // 16 KB
    ushort* sB0 = smem + 16384;    //  8 KB
    ushort* sB1 = smem + 20480;    //  8 KB
    float* fOut = (float*)smem;    // epilogue reuse: [64 co][132] f32 (33.8 KB)
    const int tid = threadIdx.x;
    const int bid = blockIdx.x;
    const int l = (bid & 7)*128 + (bid >> 3);  // 1024 blocks, cot fastest per XCD
    const int cotile = l & 7;                  // 0..7
    const int mtile  = l >> 3;                 // 0..127
    const int co0 = cotile * 64;
    const int m0  = mtile * 128;
    const int n = m0 >> 12, t0 = m0 & 4095;
    const ushort* Abase = ctx + (size_t)m0*CC;
    const ushort* Bbase = Wob + (size_t)co0*CC;
    const int w = tid >> 6, lane = tid & 63;
    const int wr = w >> 1, wc = w & 1;
    const int l15 = lane & 15, quad = lane >> 4;

    const int mr = tid >> 3;
    const int kk = (tid & 7) ^ (mr & 7);
    const ushort* gA0 = Abase + (size_t)mr*CC + kk*8;
    const ushort* gB0 = Bbase + (size_t)mr*CC + kk*8;
    const int lS = (tid & ~63) * 8;

    // prologue: kb=0 into buf0
    #pragma unroll
    for (int i = 0; i < 4; ++i) gload16(gA0 + (size_t)i*32*CC, sA0 + lS + i*2048);
    #pragma unroll
    for (int i = 0; i < 2; ++i) gload16(gB0 + (size_t)i*32*CC, sB0 + lS + i*2048);

    f32x4 acc[4][2] = {};
    for (int kb = 0; kb < 8; ++kb){
        ushort* sAc = (kb & 1) ? sA1 : sA0;
        ushort* sBc = (kb & 1) ? sB1 : sB0;
        ushort* sAn = (kb & 1) ? sA0 : sA1;
        ushort* sBn = (kb & 1) ? sB0 : sB1;
        __syncthreads();           // buf(kb) landed+visible; MFMA(kb-1) readers done
        if (kb < 7){
            #pragma unroll
            for (int i = 0; i < 4; ++i)
                gload16(gA0 + (size_t)i*32*CC + (kb+1)*64, sAn + lS + i*2048);
            #pragma unroll
            for (int i = 0; i < 2; ++i)
                gload16(gB0 + (size_t)i*32*CC + (kb+1)*64, sBn + lS + i*2048);
        }
        #pragma unroll
        for (int ks = 0; ks < 2; ++ks){
            short8 aF[4], bF[2];
            #pragma unroll
            for (int mi = 0; mi < 4; ++mi){
                int m = wr*64 + mi*16 + l15;
                aF[mi] = *(const short8*)&sAc[(m*8 + ((ks*4 + quad) ^ (m & 7)))*8];
            }
            #pragma unroll
            for (int ni = 0; ni < 2; ++ni){
                int m = wc*32 + ni*16 + l15;
                bF[ni] = *(const short8*)&sBc[(m*8 + ((ks*4 + quad) ^ (m & 7)))*8];
            }
            #pragma unroll
            for (int mi = 0; mi < 4; ++mi)
                #pragma unroll
                for (int ni = 0; ni < 2; ++ni)
                    acc[mi][ni] = __builtin_amdgcn_mfma_f32_16x16x32_bf16(
                        aF[mi], bF[ni], acc[mi][ni], 0, 0, 0);
        }
    }
    float bo[2];
    for (int ni = 0; ni < 2; ++ni) bo[ni] = b_out[co0 + wc*32 + ni*16 + l15];

    __syncthreads();                 // staging done; reuse LDS as fOut[co][t]
    for (int mi = 0; mi < 4; ++mi){
        int tl = wr*64 + mi*16 + quad*4;
        for (int ni = 0; ni < 2; ++ni){
            int cl = wc*32 + ni*16 + l15;
            f32x4 vv;
            for (int r = 0; r < 4; ++r) vv[r] = acc[mi][ni][r] + bo[ni];
            *(f32x4*)&fOut[cl*132 + tl] = vv;
        }
    }
    __syncthreads();
    for (int i = 0; i < 8; ++i){
        int flat = i*256 + tid;
        int co = flat >> 5, ts = (flat & 31)*4;
        f32x4 a = *(const f32x4*)&fOut[co*132 + ts];
        f32x4 mk = *(const f32x4*)(masks + (size_t)n*TT + t0 + ts);
        f32x4 xv = *(const f32x4*)(x + ((size_t)n*CC + co0 + co)*TT + t0 + ts);
        f32x4 o;
        for (int r = 0; r < 4; ++r) o[r] = a[r]*mk[r] + xv[r];
        *(f32x4*)(out + ((size_t)n*CC + co0 + co)*TT + t0 + ts) = o;
    }
}

// ---------------- K4: InstanceNorm over T per (n,c), in place ----------------
__global__ __launch_bounds__(256) void inorm(float* __restrict__ out){
    __shared__ float sS[4], sQ2[4];
    float* row = out + (size_t)blockIdx.x * TT;
    f32x4 vbuf[4];
    float s = 0.f, ss = 0.f;
    for (int i = 0; i < 4; ++i){
        f32x4 vv = *(const f32x4*)(row + (size_t)(i*256 + threadIdx.x)*4);
        vbuf[i] = vv;
        for (int r = 0; r < 4; ++r){ s += vv[r]; ss += vv[r]*vv[r]; }
    }
    for (int d = 1; d < 64; d <<= 1){ s += __shfl_xor(s, d); ss += __shfl_xor(ss, d); }
    int w = threadIdx.x >> 6;
    if ((threadIdx.x & 63) == 0){ sS[w] = s; sQ2[w] = ss; }
    __syncthreads();
    s  = sS[0] + sS[1] + sS[2] + sS[3];
    ss = sQ2[0] + sQ2[1] + sQ2[2] + sQ2[3];
    float mean = s * (1.0f/TT);
    float var  = ss * (1.0f/TT) - mean*mean;
    float rstd = rsqrtf(var + 1e-5f);
    for (int i = 0; i < 4; ++i){
        f32x4 vv = vbuf[i], o;
        for (int r = 0; r < 4; ++r) o[r] = (vv[r] - mean) * rstd;
        *(f32x4*)(row + (size_t)(i*256 + threadIdx.x)*4) = o;
    }
}

extern "C" void kernel_launch(void* const* d_in, const int* in_sizes, int n_in,
                              void* d_out, int out_size, void* d_ws, size_t ws_size,
                              hipStream_t stream) {
    const float* x     = (const float*)d_in[0];
    const float* q     = (const float*)d_in[1];
    const float* k     = (const float*)d_in[2];
    const float* v     = (const float*)d_in[3];
    const float* masks = (const float*)d_in[4];
    const float* W_in  = (const float*)d_in[5];
    const float* b_in  = (const float*)d_in[6];
    const float* W_out = (const float*)d_in[7];
    const float* b_out = (const float*)d_in[8];
    float* out = (float*)d_out;

    ushort* ws  = (ushort*)d_ws;
    ushort* ctx = ws;                           // NTC bf16 (attention output)
    ushort* Wb  = ws + (size_t)NTC;             // 786432
    ushort* Wob = Wb + 786432;                  // 262144
    ushort* P   = Wob + 262144;                 // NB*TT*CQK (Q,K projected)
    ushort* Vt  = P + (size_t)NB*TT*CQK;        // NTC (V projected, transposed)

    wcvt<<<256, 256, 0, stream>>>(W_in, W_out, Wb, Wob);
    proj_gemm<<<1536, 256, 0, stream>>>(q, k, v, Wb, b_in, P, Vt);
    attn_kernel<<<2048, 256, 0, stream>>>(P, Vt, masks, ctx);
    out_gemm<<<1024, 256, 0, stream>>>(ctx, Wob, b_out, x, masks, out);
    inorm<<<2048, 256, 0, stream>>>(out);
}

// Round 3
// 238.923 us; speedup vs baseline: 1.0171x; 1.0137x over previous
//
#include <hip/hip_runtime.h>
#include <hip/hip_bf16.h>

#define NB 4
#define CC 512
#define TT 4096
#define C3 1536
#define CQK 1024
#define NTC (NB*TT*CC)   // 8388608 elems per [N,T,C] tensor

typedef __attribute__((ext_vector_type(4))) float f32x4;
typedef __attribute__((ext_vector_type(8))) short short8;
typedef unsigned short ushort;
typedef __attribute__((ext_vector_type(8))) ushort u16x8;

#define SBAR()  __builtin_amdgcn_s_barrier()
#define SCHED0() __builtin_amdgcn_sched_barrier(0)
#define WAITV(n) asm volatile("s_waitcnt vmcnt(" #n ")" ::: "memory")
#define WAITLG() asm volatile("s_waitcnt lgkmcnt(0)" ::: "memory")

__device__ __forceinline__ ushort f2bf(float f){
    union { float f; unsigned u; } x; x.f = f;
    unsigned r = x.u + 0x7fffu + ((x.u >> 16) & 1u);   // RNE
    return (ushort)(r >> 16);
}

__device__ __forceinline__ ushort2 pk2bf(float a, float b){
    float2 f2; f2.x = a; f2.y = b;
    __hip_bfloat162 h = __float22bfloat162_rn(f2);     // v_cvt_pk_bf16_f32 (RNE)
    union { __hip_bfloat162 h2; ushort2 u2; } u; u.h2 = h;
    return u.u2;
}

__device__ __forceinline__ void gload16(const void* g, void* l){
    __builtin_amdgcn_global_load_lds((const __attribute__((address_space(1))) void*)g,
                                     (__attribute__((address_space(3))) void*)l,
                                     16, 0, 0);
}

// sA swizzle: 16B slot position for logical c-block cb at row m.
__device__ __forceinline__ int apos(int m, int cb){
    return (m*8 + ((cb + m + (m >> 3)) & 7))*8;
}

// ---------------- K0: weight fp32 -> bf16 ----------------
__global__ __launch_bounds__(256) void wcvt(const float* __restrict__ Wi,
                                            const float* __restrict__ Wo,
                                            ushort* __restrict__ Wb,
                                            ushort* __restrict__ Wob){
    int idx0 = blockIdx.x * 1024 + threadIdx.x;
    for (int i = 0; i < 4; ++i){
        int idx = idx0 + i*256;
        const float* src; ushort* dst; int j;
        if (idx < 196608){ src = Wi; dst = Wb;  j = idx; }
        else             { src = Wo; dst = Wob; j = idx - 196608; }
        f32x4 vv = *((const f32x4*)src + j);
        ushort4 o;
        *(ushort2*)&o.x = pk2bf(vv[0], vv[1]);
        *(ushort2*)&o.z = pk2bf(vv[2], vv[3]);
        *((ushort4*)dst + j) = o;
    }
}

// ---------------- K1: fused transpose+cvt + QKV projection GEMM ----------------
// Counted-vmcnt pipeline (raw s_barrier, no drain-0 in the loop):
//   A reg-loads issued 2 K-steps ahead (double reg set aE/aO);
//   B global_load_lds issued 1 K-step ahead (dbuf);
//   per kb: vmcnt(12) waits only ops issued a full kb earlier -> ~0 stall.
// Queue at the wait (kb=0..5): [A(kb+1)x8, B(kb)x4 | A(kb+2)x8, B(kb+1)x4]
//   -> vmcnt(12) drains exactly through B(kb). kb=6: vmcnt(4); kb=7: vmcnt(0).
__global__ __launch_bounds__(256) void proj_gemm(const float* __restrict__ q,
                                                 const float* __restrict__ k,
                                                 const float* __restrict__ v,
                                                 const ushort* __restrict__ Wb,
                                                 const float* __restrict__ b_in,
                                                 ushort* __restrict__ P,
                                                 ushort* __restrict__ Vt){
    __shared__ __align__(16) ushort smem[24576];   // 48 KB
    ushort* sA  = smem;            // 16 KB  (bf16 A, swizzled, single buffer)
    ushort* sB0 = smem + 8192;     // 16 KB
    ushort* sB1 = smem + 16384;    // 16 KB
    const int tid = threadIdx.x;
    const int bid = blockIdx.x;
    const int mtile  = ((bid & 7) << 4) | ((bid >> 3) & 15);
    const int cotile = bid >> 7;               // 0..11
    const int co0 = cotile * 128;
    const int m0  = mtile * 128;
    const int which = co0 >> 9;                // 0:q 1:k 2:v
    const float* src = (which == 0) ? q : (which == 1) ? k : v;
    const int n  = m0 >> 12, t0 = m0 & 4095;
    const ushort* Bbase = Wb + (size_t)co0*CC;
    const int w = tid >> 6, lane = tid & 63;
    const int wr = w >> 1, wc = w & 1;
    const int l15 = lane & 15, quad = lane >> 4;
    const int hlf = lane >> 5, tq = lane & 31;

    const int mrB = tid >> 3;
    const int kkB = (tid & 7) ^ (mrB & 7);
    const ushort* gB0 = Bbase + (size_t)mrB*CC + kkB*8;
    const int lB0 = (tid & ~63) * 8;

    const float* Ab = src + (size_t)n*CC*TT + t0 + tq*4;
    const int ce0 = w*16 + hlf*2;              // + u*4 per unit

    f32x4 aE[8], aO[8];   // [2u]=row ce0+4u, [2u+1]=row+1

#define LOADA(dst, cbase) do{                                              \
    const float* _p = Ab + (size_t)(cbase)*TT;                             \
    _Pragma("unroll")                                                      \
    for (int u = 0; u < 4; ++u){                                           \
        dst[2*u]   = *(const f32x4*)(_p + (size_t)(ce0 + u*4    )*TT);     \
        dst[2*u+1] = *(const f32x4*)(_p + (size_t)(ce0 + u*4 + 1)*TT);     \
    } }while(0)

#define LOADB(buf, koff) do{                                               \
    _Pragma("unroll")                                                      \
    for (int i = 0; i < 4; ++i)                                            \
        gload16(gB0 + (size_t)i*32*CC + (koff), (buf) + lB0 + i*2048);     \
    }while(0)

#define CVTA(sr) do{                                                       \
    _Pragma("unroll")                                                      \
    for (int u = 0; u < 4; ++u){                                           \
        int ce = ce0 + u*4; int cb = ce >> 3, off = ce & 7;                \
        _Pragma("unroll")                                                  \
        for (int j = 0; j < 4; ++j)                                        \
            *(ushort2*)&sA[apos(tq*4 + j, cb) + off] =                     \
                pk2bf(sr[2*u][j], sr[2*u+1][j]);                           \
    } }while(0)

#define MFMAPH(sBc) do{                                                    \
    _Pragma("unroll")                                                      \
    for (int ks = 0; ks < 2; ++ks){                                        \
        short8 aF[4], bF[4];                                               \
        _Pragma("unroll")                                                  \
        for (int mi = 0; mi < 4; ++mi){                                    \
            int m = wr*64 + mi*16 + l15;                                   \
            aF[mi] = *(const short8*)&sA[apos(m, ks*4 + quad)];            \
        }                                                                  \
        _Pragma("unroll")                                                  \
        for (int ni = 0; ni < 4; ++ni){                                    \
            int m = wc*64 + ni*16 + l15;                                   \
            bF[ni] = *(const short8*)&(sBc)[(m*8 + ((ks*4 + quad) ^ (m & 7)))*8]; \
        }                                                                  \
        _Pragma("unroll")                                                  \
        for (int mi = 0; mi < 4; ++mi)                                     \
            _Pragma("unroll")                                              \
            for (int ni = 0; ni < 4; ++ni)                                 \
                acc[mi][ni] = __builtin_amdgcn_mfma_f32_16x16x32_bf16(     \
                    aF[mi], bF[ni], acc[mi][ni], 0, 0, 0);                 \
    } }while(0)

#define PITER(kb, Lset, Cset, sBc, sBn) do{                                \
    if ((kb) < 6) LOADA(Lset, ((kb)+2)*64);                                \
    if ((kb) < 7) LOADB(sBn, ((kb)+1)*64);                                 \
    SCHED0();                                                              \
    if ((kb) < 6)      { WAITV(12); }                                      \
    else if ((kb) == 6){ WAITV(4);  }                                      \
    else               { WAITV(0);  }                                      \
    WAITLG();                                                              \
    SBAR();            /* B(kb) + sA(kb) visible to all waves */           \
    SCHED0();                                                              \
    MFMAPH(sBc);                                                           \
    SBAR();            /* all waves done reading sA(kb) (no drain) */      \
    SCHED0();                                                              \
    if ((kb) < 7) CVTA(Cset);                                              \
    }while(0)

    f32x4 acc[4][4] = {};
    // prologue: A(0)->aE, B(0)->sB0, A(1)->aO, cvt A(0)->sA
    LOADA(aE, 0);
    LOADB(sB0, 0);
    LOADA(aO, 64);
    CVTA(aE);          // compiler inserts the reg-dependency vmcnt wait
    for (int kb2 = 0; kb2 < 8; kb2 += 2){
        PITER(kb2,     aE, aO, sB0, sB1);
        PITER(kb2 + 1, aO, aE, sB1, sB0);
    }

#undef LOADA
#undef LOADB
#undef CVTA
#undef MFMAPH
#undef PITER

    float bj[4];
    for (int ni = 0; ni < 4; ++ni) bj[ni] = b_in[co0 + wc*64 + ni*16 + l15];

    __syncthreads();                 // done with staging; reuse as sOut[128][136]
    ushort* sOut = smem;
    if (which < 2){
        for (int mi = 0; mi < 4; ++mi){
            int mrow = wr*64 + mi*16 + quad*4;
            for (int ni = 0; ni < 4; ++ni){
                int col = wc*64 + ni*16 + l15;
                for (int r = 0; r < 4; ++r)
                    sOut[(mrow + r)*136 + col] = f2bf(acc[mi][ni][r] + bj[ni]);
            }
        }
    } else {
        for (int mi = 0; mi < 4; ++mi){
            int mrow = wr*64 + mi*16 + quad*4;
            for (int ni = 0; ni < 4; ++ni){
                int col = wc*64 + ni*16 + l15;
                ushort4 o4;
                o4.x = f2bf(acc[mi][ni][0] + bj[ni]);
                o4.y = f2bf(acc[mi][ni][1] + bj[ni]);
                o4.z = f2bf(acc[mi][ni][2] + bj[ni]);
                o4.w = f2bf(acc[mi][ni][3] + bj[ni]);
                *(ushort4*)&sOut[col*136 + mrow] = o4;   // mrow%4==0, contiguous
            }
        }
    }
    __syncthreads();
    if (which < 2){
        for (int i = 0; i < 8; ++i){
            int flat = i*256 + tid;
            int row = flat >> 4, cs = (flat & 15)*8;
            u16x8 val = *(const u16x8*)&sOut[row*136 + cs];
            *(u16x8*)(P + (size_t)(m0 + row)*CQK + which*512 + (co0 & 511) + cs) = val;
        }
    } else {
        for (int i = 0; i < 8; ++i){
            int flat = i*256 + tid;
            int row = flat >> 4, cs = (flat & 15)*8;    // row = local co (d), cs along t
            int cl = (co0 - 1024) + row;
            int h = cl >> 6, d = cl & 63;
            u16x8 val = *(const u16x8*)&sOut[row*136 + cs];
            *(u16x8*)(Vt + (((size_t)n*8 + h)*64 + d)*TT + t0 + cs) = val;
        }
    }
}

// ---------------- K2: per-(n,chunk,head) attention (LDS epilogue) ----------------
__global__ __launch_bounds__(256) void attn_kernel(const ushort* __restrict__ P,
                                                   const ushort* __restrict__ Vt,
                                                   const float* __restrict__ masks,
                                                   ushort* __restrict__ ctx){
    __shared__ __align__(16) ushort sQ[64*64], sK[64*64], sV[64*64];   // swizzled
    __shared__ __align__(16) ushort sP[64][72];
    __shared__ __align__(16) ushort sO[64*72];
    int bid = blockIdx.x;
    int l = (bid & 7)*256 + (bid >> 3);        // 2048 blocks, h fastest per XCD
    int h = l & 7, ch = (l >> 3) & 63, n = l >> 9;
    const int tid = threadIdx.x, lane = tid & 63, w = tid >> 6;
    const int l15 = lane & 15, quad = lane >> 4;
    const size_t rowbase = (size_t)n*TT + (size_t)ch*64;
    for (int i = 0; i < 2; ++i){
        int slot = i*256 + tid;
        int r = slot >> 3, k8 = slot & 7, kk = k8 ^ (r & 7);
        int lbase = (i*256 + (tid & ~63)) * 8;
        const ushort* gq = P + (rowbase + r)*CQK + h*64 + kk*8;
        gload16(gq,        sQ + lbase);
        gload16(gq + 512,  sK + lbase);
        const ushort* gv = Vt + (((size_t)n*8 + h)*64 + r)*TT + ch*64 + kk*8;
        gload16(gv,        sV + lbase);
    }
    __syncthreads();
    const int m0w = w*16;
    short8 aQ[2]; f32x4 accS[4] = {};
    for (int ks = 0; ks < 2; ++ks){
        int m = m0w + l15;
        aQ[ks] = *(const short8*)&sQ[(m*8 + ((ks*4 + quad) ^ (m & 7)))*8];
    }
    for (int ni = 0; ni < 4; ++ni)
        for (int ks = 0; ks < 2; ++ks){
            int m = ni*16 + l15;
            short8 bK = *(const short8*)&sK[(m*8 + ((ks*4 + quad) ^ (m & 7)))*8];
            accS[ni] = __builtin_amdgcn_mfma_f32_16x16x32_bf16(aQ[ks], bK, accS[ni], 0,0,0);
        }
    float madd[4];
    for (int ni = 0; ni < 4; ++ni){
        float mv = masks[(size_t)n*TT + ch*64 + ni*16 + l15];
        madd[ni] = (mv > 0.f) ? 0.f : -1e9f;
    }
    float s[4][4];
    for (int ni = 0; ni < 4; ++ni)
        for (int r = 0; r < 4; ++r) s[ni][r] = accS[ni][r]*0.125f + madd[ni];
    float ex[4][4];
    for (int r = 0; r < 4; ++r){
        float m1 = fmaxf(fmaxf(s[0][r], s[1][r]), fmaxf(s[2][r], s[3][r]));
        for (int d = 1; d < 16; d <<= 1) m1 = fmaxf(m1, __shfl_xor(m1, d));
        float a = 0.f;
        for (int ni = 0; ni < 4; ++ni){ float e = __expf(s[ni][r] - m1); ex[ni][r] = e; a += e; }
        for (int d = 1; d < 16; d <<= 1) a += __shfl_xor(a, d);
        float rs = 1.0f / a;
        for (int ni = 0; ni < 4; ++ni)
            sP[m0w + quad*4 + r][ni*16 + l15] = f2bf(ex[ni][r] * rs);
    }
    short8 aP[2]; f32x4 accO[4] = {};
    for (int ks = 0; ks < 2; ++ks)
        aP[ks] = *(const short8*)&sP[m0w + l15][ks*32 + quad*8];
    for (int ni = 0; ni < 4; ++ni)
        for (int ks = 0; ks < 2; ++ks){
            int m = ni*16 + l15;
            short8 bV = *(const short8*)&sV[(m*8 + ((ks*4 + quad) ^ (m & 7)))*8];
            accO[ni] = __builtin_amdgcn_mfma_f32_16x16x32_bf16(aP[ks], bV, accO[ni], 0,0,0);
        }
    for (int ni = 0; ni < 4; ++ni)
        for (int r = 0; r < 4; ++r)
            sO[(m0w + quad*4 + r)*72 + ni*16 + l15] = f2bf(accO[ni][r]);
    __syncthreads();
    for (int i = 0; i < 2; ++i){
        int flat = i*256 + tid;
        int row = flat >> 3, cs = (flat & 7)*8;
        u16x8 val = *(const u16x8*)&sO[row*72 + cs];
        *(u16x8*)(ctx + (rowbase + row)*CC + h*64 + cs) = val;
    }
}

// ---------------- K3: out-projection, triple-buffered counted-vmcnt ----------------
// g(kb+2) issued right after the top barrier of kb; vmcnt(6) waits g(kb),
// issued two K-steps earlier -> ~0 stall. One raw barrier per kb, no drain-0.
__global__ __launch_bounds__(256) void out_gemm(const ushort* __restrict__ ctx,
                                                const ushort* __restrict__ Wob,
                                                const float* __restrict__ b_out,
                                                const float* __restrict__ x,
                                                const float* __restrict__ masks,
                                                float* __restrict__ out){
    __shared__ __align__(16) ushort smem[36864];   // 72 KB: A 3x16K + B 3x8K
    ushort* sA0 = smem;
    ushort* sA1 = smem + 8192;
    ushort* sA2 = smem + 16384;
    ushort* sB0 = smem + 24576;
    ushort* sB1 = smem + 28672;
    ushort* sB2 = smem + 32768;
    float* fOut = (float*)smem;    // epilogue reuse: [64 co][132] f32 (33.8 KB)
    const int tid = threadIdx.x;
    const int bid = blockIdx.x;
    const int l = (bid & 7)*128 + (bid >> 3);  // 1024 blocks, cot fastest per XCD
    const int cotile = l & 7;                  // 0..7
    const int mtile  = l >> 3;                 // 0..127
    const int co0 = cotile * 64;
    const int m0  = mtile * 128;
    const int n = m0 >> 12, t0 = m0 & 4095;
    const ushort* Abase = ctx + (size_t)m0*CC;
    const ushort* Bbase = Wob + (size_t)co0*CC;
    const int w = tid >> 6, lane = tid & 63;
    const int wr = w >> 1, wc = w & 1;
    const int l15 = lane & 15, quad = lane >> 4;

    const int mr = tid >> 3;
    const int kk = (tid & 7) ^ (mr & 7);
    const ushort* gA0 = Abase + (size_t)mr*CC + kk*8;
    const ushort* gB0 = Bbase + (size_t)mr*CC + kk*8;
    const int lS = (tid & ~63) * 8;

#define OLOAD(sAn, sBn, koff) do{                                          \
    _Pragma("unroll")                                                      \
    for (int i = 0; i < 4; ++i)                                            \
        gload16(gA0 + (size_t)i*32*CC + (koff), (sAn) + lS + i*2048);      \
    _Pragma("unroll")                                                      \
    for (int i = 0; i < 2; ++i)                                            \
        gload16(gB0 + (size_t)i*32*CC + (koff), (sBn) + lS + i*2048);      \
    }while(0)

#define OITER(kb, sAc, sBc, sAn, sBn) do{                                  \
    SCHED0();                                                              \
    if ((kb) < 7) { WAITV(6); } else { WAITV(0); }                         \
    SBAR();                                                                \
    SCHED0();                                                              \
    if ((kb) < 6) OLOAD(sAn, sBn, ((kb)+2)*64);                            \
    _Pragma("unroll")                                                      \
    for (int ks = 0; ks < 2; ++ks){                                        \
        short8 aF[4], bF[2];                                               \
        _Pragma("unroll")                                                  \
        for (int mi = 0; mi < 4; ++mi){                                    \
            int m = wr*64 + mi*16 + l15;                                   \
            aF[mi] = *(const short8*)&(sAc)[(m*8 + ((ks*4 + quad) ^ (m & 7)))*8]; \
        }                                                                  \
        _Pragma("unroll")                                                  \
        for (int ni = 0; ni < 2; ++ni){                                    \
            int m = wc*32 + ni*16 + l15;                                   \
            bF[ni] = *(const short8*)&(sBc)[(m*8 + ((ks*4 + quad) ^ (m & 7)))*8]; \
        }                                                                  \
        _Pragma("unroll")                                                  \
        for (int mi = 0; mi < 4; ++mi)                                     \
            _Pragma("unroll")                                              \
            for (int ni = 0; ni < 2; ++ni)                                 \
                acc[mi][ni] = __builtin_amdgcn_mfma_f32_16x16x32_bf16(     \
                    aF[mi], bF[ni], acc[mi][ni], 0, 0, 0);                 \
    } }while(0)

    f32x4 acc[4][2] = {};
    // prologue: g(0)->bufs0, g(1)->bufs1
    OLOAD(sA0, sB0, 0);
    OLOAD(sA1, sB1, 64);
    OITER(0, sA0, sB0, sA2, sB2);
    OITER(1, sA1, sB1, sA0, sB0);
    OITER(2, sA2, sB2, sA1, sB1);
    OITER(3, sA0, sB0, sA2, sB2);
    OITER(4, sA1, sB1, sA0, sB0);
    OITER(5, sA2, sB2, sA1, sB1);
    OITER(6, sA0, sB0, sA2, sB2);
    OITER(7, sA1, sB1, sA0, sB0);

#undef OLOAD
#undef OITER

    float bo[2];
    for (int ni = 0; ni < 2; ++ni) bo[ni] = b_out[co0 + wc*32 + ni*16 + l15];

    __syncthreads();                 // staging done; reuse LDS as fOut[co][t]
    for (int mi = 0; mi < 4; ++mi){
        int tl = wr*64 + mi*16 + quad*4;
        for (int ni = 0; ni < 2; ++ni){
            int cl = wc*32 + ni*16 + l15;
            f32x4 vv;
            for (int r = 0; r < 4; ++r) vv[r] = acc[mi][ni][r] + bo[ni];
            *(f32x4*)&fOut[cl*132 + tl] = vv;
        }
    }
    __syncthreads();
    for (int i = 0; i < 8; ++i){
        int flat = i*256 + tid;
        int co = flat >> 5, ts = (flat & 31)*4;
        f32x4 a = *(const f32x4*)&fOut[co*132 + ts];
        f32x4 mk = *(const f32x4*)(masks + (size_t)n*TT + t0 + ts);
        f32x4 xv = *(const f32x4*)(x + ((size_t)n*CC + co0 + co)*TT + t0 + ts);
        f32x4 o;
        for (int r = 0; r < 4; ++r) o[r] = a[r]*mk[r] + xv[r];
        *(f32x4*)(out + ((size_t)n*CC + co0 + co)*TT + t0 + ts) = o;
    }
}

// ---------------- K4: InstanceNorm over T per (n,c), in place ----------------
__global__ __launch_bounds__(256) void inorm(float* __restrict__ out){
    __shared__ float sS[4], sQ2[4];
    float* row = out + (size_t)blockIdx.x * TT;
    f32x4 vbuf[4];
    float s = 0.f, ss = 0.f;
    for (int i = 0; i < 4; ++i){
        f32x4 vv = *(const f32x4*)(row + (size_t)(i*256 + threadIdx.x)*4);
        vbuf[i] = vv;
        for (int r = 0; r < 4; ++r){ s += vv[r]; ss += vv[r]*vv[r]; }
    }
    for (int d = 1; d < 64; d <<= 1){ s += __shfl_xor(s, d); ss += __shfl_xor(ss, d); }
    int w = threadIdx.x >> 6;
    if ((threadIdx.x & 63) == 0){ sS[w] = s; sQ2[w] = ss; }
    __syncthreads();
    s  = sS[0] + sS[1] + sS[2] + sS[3];
    ss = sQ2[0] + sQ2[1] + sQ2[2] + sQ2[3];
    float mean = s * (1.0f/TT);
    float var  = ss * (1.0f/TT) - mean*mean;
    float rstd = rsqrtf(var + 1e-5f);
    for (int i = 0; i < 4; ++i){
        f32x4 vv = vbuf[i], o;
        for (int r = 0; r < 4; ++r) o[r] = (vv[r] - mean) * rstd;
        *(f32x4*)(row + (size_t)(i*256 + threadIdx.x)*4) = o;
    }
}

extern "C" void kernel_launch(void* const* d_in, const int* in_sizes, int n_in,
                              void* d_out, int out_size, void* d_ws, size_t ws_size,
                              hipStream_t stream) {
    const float* x     = (const float*)d_in[0];
    const float* q     = (const float*)d_in[1];
    const float* k     = (const float*)d_in[2];
    const float* v     = (const float*)d_in[3];
    const float* masks = (const float*)d_in[4];
    const float* W_in  = (const float*)d_in[5];
    const float* b_in  = (const float*)d_in[6];
    const float* W_out = (const float*)d_in[7];
    const float* b_out = (const float*)d_in[8];
    float* out = (float*)d_out;

    ushort* ws  = (ushort*)d_ws;
    ushort* ctx = ws;                           // NTC bf16 (attention output)
    ushort* Wb  = ws + (size_t)NTC;             // 786432
    ushort* Wob = Wb + 786432;                  // 262144
    ushort* P   = Wob + 262144;                 // NB*TT*CQK (Q,K projected)
    ushort* Vt  = P + (size_t)NB*TT*CQK;        // NTC (V projected, transposed)

    wcvt<<<256, 256, 0, stream>>>(W_in, W_out, Wb, Wob);
    proj_gemm<<<1536, 256, 0, stream>>>(q, k, v, Wb, b_in, P, Vt);
    attn_kernel<<<2048, 256, 0, stream>>>(P, Vt, masks, ctx);
    out_gemm<<<1024, 256, 0, stream>>>(ctx, Wob, b_out, x, masks, out);
    inorm<<<2048, 256, 0, stream>>>(out);
}